// Round 1
// baseline (2953.544 us; speedup 1.0000x reference)
//
#include <hip/hip_runtime.h>
#include <hip/hip_bf16.h>
#include <math.h>

typedef unsigned short u16;
typedef unsigned int   u32;

#define EPS_H 0.01f

__device__ __forceinline__ u16 f2bf(float f) {
    u32 x = __float_as_uint(f);
    return (u16)((x + 0x7fffu + ((x >> 16) & 1u)) >> 16);   // RNE
}
__device__ __forceinline__ float bfs(u16 v) { return __uint_as_float(((u32)v) << 16); }
__device__ __forceinline__ float selu_f(float x) {
    const float sc = 1.0507009873554805f, al = 1.6732632423543772f;
    return x > 0.f ? sc * x : sc * al * expm1f(x);
}
__device__ __forceinline__ float gelu_f(float x) {
    return 0.5f * x * (1.f + erff(x * 0.7071067811865476f));
}
__device__ __forceinline__ float pe_val(int n, int j) {
    float t = 1000.0f * ((float)(j & ~1) * (1.0f / 512.0f)) + 0.01f;
    float a = (float)n / t;
    return (j & 1) ? cosf(a) : sinf(a);
}

// ---------------- K1: qkv = selu(x @ Wqkv[h] + bqkv[h]) -> bf16 [32768][1536]
__global__ __launch_bounds__(256)
void k_qkv(const float* __restrict__ x, const float* __restrict__ W,
           const float* __restrict__ bias, u16* __restrict__ qkv)
{
    __shared__ float As[16][68];
    __shared__ float Bs[16][68];
    const int tid  = threadIdx.x;
    const int col0 = blockIdx.x * 64;
    const int row0 = blockIdx.y * 64;
    const int tm = tid >> 4, tn = tid & 15;
    const int lm = tid >> 2, lk = (tid & 3) << 2;   // x tile load
    const int wk = tid >> 4, wn = (tid & 15) << 2;  // W tile load
    float acc[4][4] = {};
    for (int k0 = 0; k0 < 512; k0 += 16) {
        float4 av = *reinterpret_cast<const float4*>(&x[(size_t)(row0 + lm) * 512 + k0 + lk]);
        float4 bv = *reinterpret_cast<const float4*>(&W[(size_t)(k0 + wk) * 1536 + col0 + wn]);
        As[lk + 0][lm] = av.x; As[lk + 1][lm] = av.y;
        As[lk + 2][lm] = av.z; As[lk + 3][lm] = av.w;
        *reinterpret_cast<float4*>(&Bs[wk][wn]) = bv;
        __syncthreads();
        #pragma unroll
        for (int kk = 0; kk < 16; ++kk) {
            float4 a4 = *reinterpret_cast<const float4*>(&As[kk][tm << 2]);
            float4 b4 = *reinterpret_cast<const float4*>(&Bs[kk][tn << 2]);
            float a[4] = {a4.x, a4.y, a4.z, a4.w};
            float b[4] = {b4.x, b4.y, b4.z, b4.w};
            #pragma unroll
            for (int i = 0; i < 4; ++i)
                #pragma unroll
                for (int j = 0; j < 4; ++j)
                    acc[i][j] = fmaf(a[i], b[j], acc[i][j]);
        }
        __syncthreads();
    }
    const float4 b4 = *reinterpret_cast<const float4*>(&bias[col0 + (tn << 2)]);
    const float bb[4] = {b4.x, b4.y, b4.z, b4.w};
    #pragma unroll
    for (int i = 0; i < 4; ++i) {
        ushort4 st;
        st.x = f2bf(selu_f(acc[i][0] + bb[0]));
        st.y = f2bf(selu_f(acc[i][1] + bb[1]));
        st.z = f2bf(selu_f(acc[i][2] + bb[2]));
        st.w = f2bf(selu_f(acc[i][3] + bb[3]));
        *reinterpret_cast<ushort4*>(&qkv[(size_t)(row0 + (tm << 2) + i) * 1536 + col0 + (tn << 2)]) = st;
    }
}

// ---------------- K2: M[seq] = (k^T v) / 512, per sequence (512x512 fp32)
__global__ __launch_bounds__(256)
void k_ktv(const u16* __restrict__ qkv, float* __restrict__ M)
{
    __shared__ float Ks[16][68];
    __shared__ float Vs[16][68];
    const int tid = threadIdx.x;
    const int seq = blockIdx.z;
    const int i0 = blockIdx.y * 64, j0 = blockIdx.x * 64;
    const int tm = tid >> 4, tn = tid & 15;
    const int lm = tid >> 4, lc = (tid & 15) << 2;
    const u16* base = qkv + (size_t)seq * 1024 * 1536;
    float acc[4][4] = {};
    for (int m0 = 0; m0 < 1024; m0 += 16) {
        ushort4 kk4 = *reinterpret_cast<const ushort4*>(&base[(size_t)(m0 + lm) * 1536 + 512 + i0 + lc]);
        ushort4 vv4 = *reinterpret_cast<const ushort4*>(&base[(size_t)(m0 + lm) * 1536 + 1024 + j0 + lc]);
        *reinterpret_cast<float4*>(&Ks[lm][lc]) = make_float4(bfs(kk4.x), bfs(kk4.y), bfs(kk4.z), bfs(kk4.w));
        *reinterpret_cast<float4*>(&Vs[lm][lc]) = make_float4(bfs(vv4.x), bfs(vv4.y), bfs(vv4.z), bfs(vv4.w));
        __syncthreads();
        #pragma unroll
        for (int kk = 0; kk < 16; ++kk) {
            float4 a4 = *reinterpret_cast<const float4*>(&Ks[kk][tm << 2]);
            float4 b4 = *reinterpret_cast<const float4*>(&Vs[kk][tn << 2]);
            float a[4] = {a4.x, a4.y, a4.z, a4.w};
            float b[4] = {b4.x, b4.y, b4.z, b4.w};
            #pragma unroll
            for (int i = 0; i < 4; ++i)
                #pragma unroll
                for (int j = 0; j < 4; ++j)
                    acc[i][j] = fmaf(a[i], b[j], acc[i][j]);
        }
        __syncthreads();
    }
    float* Mo = M + (size_t)seq * 262144;
    #pragma unroll
    for (int i = 0; i < 4; ++i) {
        float4 st = make_float4(acc[i][0] * 0.001953125f, acc[i][1] * 0.001953125f,
                                acc[i][2] * 0.001953125f, acc[i][3] * 0.001953125f);
        *reinterpret_cast<float4*>(&Mo[(size_t)(i0 + (tm << 2) + i) * 512 + j0 + (tn << 2)]) = st;
    }
}

// ---------------- K3: fused  S3 = q@M ; att = softmax_d(S3) ; proj = gelu(att@Wp + bp)
//                  accum==0: out = EPS*proj + pe   |  accum==1: out += proj
__global__ __launch_bounds__(256)
void k_attn(const u16* __restrict__ qkv, const float* __restrict__ M,
            const float* __restrict__ Wp, const float* __restrict__ bp,
            float* __restrict__ out, const int accum)
{
    __shared__ __align__(16) u16 tile[32][512];   // q (bf16), then att (bf16)
    __shared__ float redA[4][32];
    __shared__ float redB[4][32];
    const int tid  = threadIdx.x;            // 256 threads
    const int wave = tid >> 6, lane = tid & 63;
    const int blk  = blockIdx.x;             // 1024 blocks
    const int seq  = blk >> 5;
    const int r0   = (blk & 31) << 5;        // 32 rows per block
    const u16* qbase = qkv + (size_t)(seq * 1024 + r0) * 1536;
    #pragma unroll
    for (int ii = 0; ii < 8; ++ii) {
        int idx = tid + (ii << 8);
        int row = idx >> 6;
        int col = (idx & 63) << 3;
        *reinterpret_cast<uint4*>(&tile[row][col]) =
            *reinterpret_cast<const uint4*>(&qbase[(size_t)row * 1536 + col]);
    }
    __syncthreads();
    const float* Ms = M + (size_t)seq * 262144;
    float acc0[32], acc1[32];
    #pragma unroll
    for (int r = 0; r < 32; ++r) { acc0[r] = 0.f; acc1[r] = 0.f; }
    for (int d0 = 0; d0 < 512; d0 += 2) {
        const float m00 = Ms[d0 * 512 + tid];
        const float m01 = Ms[(d0 + 1) * 512 + tid];
        const float m10 = Ms[d0 * 512 + tid + 256];
        const float m11 = Ms[(d0 + 1) * 512 + tid + 256];
        #pragma unroll
        for (int r = 0; r < 32; ++r) {
            const u32 u = *reinterpret_cast<const u32*>(&tile[r][d0]);
            const float q0 = __uint_as_float(u << 16);
            const float q1 = __uint_as_float(u & 0xffff0000u);
            acc0[r] = fmaf(q1, m01, fmaf(q0, m00, acc0[r]));
            acc1[r] = fmaf(q1, m11, fmaf(q0, m10, acc1[r]));
        }
    }
    // row softmax over 512 cols (thread owns cols tid and tid+256)
    #pragma unroll
    for (int r = 0; r < 32; ++r) {
        float m = fmaxf(acc0[r], acc1[r]);
        #pragma unroll
        for (int off = 32; off > 0; off >>= 1) m = fmaxf(m, __shfl_xor(m, off));
        if (lane == 0) redA[wave][r] = m;
    }
    __syncthreads();
    #pragma unroll
    for (int r = 0; r < 32; ++r) {
        const float m = fmaxf(fmaxf(redA[0][r], redA[1][r]), fmaxf(redA[2][r], redA[3][r]));
        const float e0 = expf(acc0[r] - m);
        const float e1 = expf(acc1[r] - m);
        acc0[r] = e0; acc1[r] = e1;
        float s = e0 + e1;
        #pragma unroll
        for (int off = 32; off > 0; off >>= 1) s += __shfl_xor(s, off);
        if (lane == 0) redB[wave][r] = s;
    }
    __syncthreads();
    #pragma unroll
    for (int r = 0; r < 32; ++r) {
        const float inv = 1.0f / (redB[0][r] + redB[1][r] + redB[2][r] + redB[3][r]);
        tile[r][tid]       = f2bf(acc0[r] * inv);
        tile[r][tid + 256] = f2bf(acc1[r] * inv);
    }
    __syncthreads();
    // proj = att @ Wp
    #pragma unroll
    for (int r = 0; r < 32; ++r) { acc0[r] = 0.f; acc1[r] = 0.f; }
    for (int d0 = 0; d0 < 512; d0 += 2) {
        const float w00 = Wp[d0 * 512 + tid];
        const float w01 = Wp[(d0 + 1) * 512 + tid];
        const float w10 = Wp[d0 * 512 + tid + 256];
        const float w11 = Wp[(d0 + 1) * 512 + tid + 256];
        #pragma unroll
        for (int r = 0; r < 32; ++r) {
            const u32 u = *reinterpret_cast<const u32*>(&tile[r][d0]);
            const float a0 = __uint_as_float(u << 16);
            const float a1 = __uint_as_float(u & 0xffff0000u);
            acc0[r] = fmaf(a1, w01, fmaf(a0, w00, acc0[r]));
            acc1[r] = fmaf(a1, w11, fmaf(a0, w10, acc1[r]));
        }
    }
    const float b0 = bp[tid], b1 = bp[tid + 256];
    float* orow = out + (size_t)(seq * 1024 + r0) * 512;
    if (accum == 0) {
        #pragma unroll
        for (int r = 0; r < 32; ++r) {
            orow[r * 512 + tid]       = EPS_H * gelu_f(acc0[r] + b0) + pe_val(r0 + r, tid);
            orow[r * 512 + tid + 256] = EPS_H * gelu_f(acc1[r] + b1) + pe_val(r0 + r, tid + 256);
        }
    } else {
        #pragma unroll
        for (int r = 0; r < 32; ++r) {
            orow[r * 512 + tid]       += gelu_f(acc0[r] + b0);
            orow[r * 512 + tid + 256] += gelu_f(acc1[r] + b1);
        }
    }
}

extern "C" void kernel_launch(void* const* d_in, const int* in_sizes, int n_in,
                              void* d_out, int out_size, void* d_ws, size_t ws_size,
                              hipStream_t stream)
{
    const float* x    = (const float*)d_in[0];
    const float* Wqkv = (const float*)d_in[1];
    const float* bqkv = (const float*)d_in[2];
    const float* Wp   = (const float*)d_in[3];
    const float* bp   = (const float*)d_in[4];
    float* out = (float*)d_out;

    u16*   qkv = (u16*)d_ws;                                              // 96 MB
    float* M   = (float*)((char*)d_ws + (size_t)32768 * 1536 * sizeof(u16)); // +32 MB

    const int heads[2] = {0, 3};   // heads 1,2 provably do not affect the output
    for (int p = 0; p < 2; ++p) {
        const int h = heads[p];
        k_qkv<<<dim3(24, 512), 256, 0, stream>>>(x, Wqkv + (size_t)h * 512 * 1536,
                                                 bqkv + (size_t)h * 1536, qkv);
        k_ktv<<<dim3(8, 8, 32), 256, 0, stream>>>(qkv, M);
        k_attn<<<dim3(1024), 256, 0, stream>>>(qkv, M, Wp + (size_t)h * 512 * 512,
                                               bp + (size_t)h * 512, out, p);
    }
}

// Round 2
// 807.900 us; speedup vs baseline: 3.6558x; 3.6558x over previous
//
#include <hip/hip_runtime.h>
#include <hip/hip_bf16.h>
#include <math.h>

typedef unsigned short u16;
typedef unsigned int   u32;
typedef __bf16  v8bf __attribute__((ext_vector_type(8)));
typedef float   v4f  __attribute__((ext_vector_type(4)));

#define EPS_H 0.01f

typedef const __attribute__((address_space(1))) void* gas_t;
typedef __attribute__((address_space(3))) void* las_t;
#define GL2LDS(g,l) __builtin_amdgcn_global_load_lds((gas_t)(const void*)(g), (las_t)(void*)(l), 16, 0, 0)

__device__ __forceinline__ u16 f2bf(float f) {
    u32 x = __float_as_uint(f);
    return (u16)((x + 0x7fffu + ((x >> 16) & 1u)) >> 16);   // RNE
}
__device__ __forceinline__ float selu_f(float x) {
    const float sc = 1.0507009873554805f, al = 1.6732632423543772f;
    return x > 0.f ? sc * x : sc * al * expm1f(x);
}
__device__ __forceinline__ float gelu_f(float x) {
    return 0.5f * x * (1.f + erff(x * 0.7071067811865476f));
}
__device__ __forceinline__ float pe_val(int n, int j) {
    float t = 1000.0f * ((float)(j & ~1) * (1.0f / 512.0f)) + 0.01f;
    float a = (float)n / t;
    return (j & 1) ? cosf(a) : sinf(a);
}

// fragment read from a swizzled [R][32]-bf16 LDS tile (row stride 64B)
__device__ __forceinline__ v8bf lfrag(const u16* base, int row, int lane) {
    int g = (lane >> 4) ^ ((row >> 1) & 3);
    return *(const v8bf*)((const char*)base + row * 64 + g * 16);
}

// ---------------- K1: qkv = selu(x @ W + b); q row-major, k/v stored transposed
__global__ __launch_bounds__(256)
void k1_qkv(const float* __restrict__ x, const u16* __restrict__ WT,
            const float* __restrict__ bias, u16* __restrict__ q,
            u16* __restrict__ kT, u16* __restrict__ vT)
{
    __shared__ u16 Als[128 * 32];
    __shared__ u16 Bls[128 * 32];
    const int tid = threadIdx.x, lane = tid & 63, wave = tid >> 6;
    const int col0 = blockIdx.x * 128, row0 = blockIdx.y * 128;
    const int wm = wave >> 1, wn = wave & 1;
    v4f acc[4][4] = {};
    for (int k0 = 0; k0 < 512; k0 += 32) {
        #pragma unroll
        for (int i = 0; i < 2; ++i) {                 // B via global_load_lds (pre-swizzled src)
            int ib = wave * 2 + i;
            int rl = ib * 16 + (lane >> 2);
            int gs = (lane & 3) ^ ((rl >> 1) & 3);
            GL2LDS((const char*)(WT + (size_t)(col0 + rl) * 512 + k0) + gs * 16,
                   (char*)Bls + ib * 1024);
        }
        #pragma unroll
        for (int i = 0; i < 4; ++i) {                 // A reg-staged fp32->bf16
            int idx = tid + i * 256;
            int r = idx >> 3, c4 = idx & 7;
            float4 xv = *(const float4*)&x[(size_t)(row0 + r) * 512 + k0 + c4 * 4];
            ushort4 bv; bv.x = f2bf(xv.x); bv.y = f2bf(xv.y); bv.z = f2bf(xv.z); bv.w = f2bf(xv.w);
            int byteo = r * 64 + ((((c4 >> 1) ^ ((r >> 1) & 3))) << 4) + ((c4 & 1) << 3);
            *(ushort4*)((char*)Als + byteo) = bv;
        }
        __syncthreads();
        v8bf av[4], bv2[4];
        #pragma unroll
        for (int f = 0; f < 4; ++f) {
            av[f]  = lfrag(Als, wm * 64 + f * 16 + (lane & 15), lane);
            bv2[f] = lfrag(Bls, wn * 64 + f * 16 + (lane & 15), lane);
        }
        #pragma unroll
        for (int i2 = 0; i2 < 4; ++i2)
            #pragma unroll
            for (int j2 = 0; j2 < 4; ++j2)
                acc[i2][j2] = __builtin_amdgcn_mfma_f32_16x16x32_bf16(av[i2], bv2[j2], acc[i2][j2], 0, 0, 0);
        __syncthreads();
    }
    const int region = col0 >> 9;   // 0:q 1:k 2:v (block-uniform)
    #pragma unroll
    for (int fn = 0; fn < 4; ++fn) {
        const int c = col0 + wn * 64 + fn * 16 + (lane & 15);
        const float bc = bias[c];
        #pragma unroll
        for (int fm = 0; fm < 4; ++fm) {
            const int rb = row0 + wm * 64 + fm * 16 + ((lane >> 4) << 2);
            float v0 = selu_f(acc[fm][fn][0] + bc);
            float v1 = selu_f(acc[fm][fn][1] + bc);
            float v2 = selu_f(acc[fm][fn][2] + bc);
            float v3 = selu_f(acc[fm][fn][3] + bc);
            if (region == 0) {
                q[(size_t)(rb + 0) * 512 + c] = f2bf(v0);
                q[(size_t)(rb + 1) * 512 + c] = f2bf(v1);
                q[(size_t)(rb + 2) * 512 + c] = f2bf(v2);
                q[(size_t)(rb + 3) * 512 + c] = f2bf(v3);
            } else {
                ushort4 st; st.x = f2bf(v0); st.y = f2bf(v1); st.z = f2bf(v2); st.w = f2bf(v3);
                const int seq = rb >> 10, n = rb & 1023;
                u16* dst = (region == 1) ? kT : vT;
                const int cc = c - ((region == 1) ? 512 : 1024);
                *(ushort4*)&dst[(size_t)seq * 524288 + (size_t)cc * 1024 + n] = st;
            }
        }
    }
}

// ---------------- K2: Mt[p][d] = (1/512) * sum_m K[m][d] V[m][p]   (per seq)
__global__ __launch_bounds__(256)
void k2_ktv(const u16* __restrict__ kT, const u16* __restrict__ vT, u16* __restrict__ Mt)
{
    __shared__ u16 Als[128 * 32];
    __shared__ u16 Bls[128 * 32];
    const int tid = threadIdx.x, lane = tid & 63, wave = tid >> 6;
    const int d0 = blockIdx.x * 128, p0 = blockIdx.y * 128, seq = blockIdx.z;
    const u16* Ab = kT + (size_t)seq * 524288;
    const u16* Bb = vT + (size_t)seq * 524288;
    const int wm = wave >> 1, wn = wave & 1;
    v4f acc[4][4] = {};
    for (int m0 = 0; m0 < 1024; m0 += 32) {
        #pragma unroll
        for (int i = 0; i < 2; ++i) {
            int ib = wave * 2 + i;
            int rl = ib * 16 + (lane >> 2);
            int gs = (lane & 3) ^ ((rl >> 1) & 3);
            GL2LDS((const char*)(Ab + (size_t)(d0 + rl) * 1024 + m0) + gs * 16, (char*)Als + ib * 1024);
            GL2LDS((const char*)(Bb + (size_t)(p0 + rl) * 1024 + m0) + gs * 16, (char*)Bls + ib * 1024);
        }
        __syncthreads();
        v8bf av[4], bv[4];
        #pragma unroll
        for (int f = 0; f < 4; ++f) {
            av[f] = lfrag(Als, wm * 64 + f * 16 + (lane & 15), lane);
            bv[f] = lfrag(Bls, wn * 64 + f * 16 + (lane & 15), lane);
        }
        #pragma unroll
        for (int i2 = 0; i2 < 4; ++i2)
            #pragma unroll
            for (int j2 = 0; j2 < 4; ++j2)
                acc[i2][j2] = __builtin_amdgcn_mfma_f32_16x16x32_bf16(av[i2], bv[j2], acc[i2][j2], 0, 0, 0);
        __syncthreads();
    }
    #pragma unroll
    for (int fn = 0; fn < 4; ++fn) {
        const int p = p0 + wn * 64 + fn * 16 + (lane & 15);
        #pragma unroll
        for (int fm = 0; fm < 4; ++fm) {
            const int d = d0 + wm * 64 + fm * 16 + ((lane >> 4) << 2);
            ushort4 st;
            st.x = f2bf(acc[fm][fn][0] * (1.f / 512.f));
            st.y = f2bf(acc[fm][fn][1] * (1.f / 512.f));
            st.z = f2bf(acc[fm][fn][2] * (1.f / 512.f));
            st.w = f2bf(acc[fm][fn][3] * (1.f / 512.f));
            *(ushort4*)&Mt[(size_t)seq * 262144 + (size_t)p * 512 + d] = st;   // transposed store
        }
    }
}

// ---------------- K3: S = q@Mt^T ; att = softmax_row(S) ; out (+)= gelu(att@WpT^T + bp) [+ EPS/pe]
__global__ __launch_bounds__(256)
void k3_attn(const u16* __restrict__ q, const u16* __restrict__ Mt,
             const u16* __restrict__ WpT, const float* __restrict__ bp,
             const float* __restrict__ pe, float* __restrict__ out, const int accum)
{
    __shared__ u16 qs[32 * 512];     // swizzled; q tile, then att tile
    __shared__ float redm[4][32];
    __shared__ float reds[4][32];
    const int tid = threadIdx.x, lane = tid & 63, wave = tid >> 6;
    const int blk = blockIdx.x;
    const int seq = blk >> 5;
    #pragma unroll
    for (int i = 0; i < 8; ++i) {    // stage q tile (swizzled: byte ^= (row&7)<<4)
        int idx = tid + i * 256;
        int r = idx >> 6, g = idx & 63;
        uint4 v = *(const uint4*)&q[(size_t)(blk * 32 + r) * 512 + g * 8];
        int gs = (g & 56) | ((g & 7) ^ (r & 7));
        *(uint4*)((char*)qs + r * 1024 + gs * 16) = v;
    }
    __syncthreads();
    const u16* Ms = Mt + (size_t)seq * 262144;
    v4f acc[2][8] = {};
    for (int k0 = 0; k0 < 512; k0 += 32) {
        int gi = (k0 >> 3) + (lane >> 4);
        int ra = lane & 15, rb = 16 + (lane & 15);
        v8bf a0 = *(const v8bf*)((const char*)qs + ra * 1024 + (((gi & 56) | ((gi & 7) ^ (ra & 7))) << 4));
        v8bf a1 = *(const v8bf*)((const char*)qs + rb * 1024 + (((gi & 56) | ((gi & 7) ^ (rb & 7))) << 4));
        #pragma unroll
        for (int fn = 0; fn < 8; ++fn) {
            int p = wave * 128 + fn * 16 + (lane & 15);
            v8bf b = *(const v8bf*)&Ms[(size_t)p * 512 + k0 + ((lane >> 4) << 3)];
            acc[0][fn] = __builtin_amdgcn_mfma_f32_16x16x32_bf16(a0, b, acc[0][fn], 0, 0, 0);
            acc[1][fn] = __builtin_amdgcn_mfma_f32_16x16x32_bf16(a1, b, acc[1][fn], 0, 0, 0);
        }
    }
    // row softmax over 512 cols (wave holds 128-col slice; lane holds rows (lane>>4)*4+j (+16fm) x 8 cols)
    float mrow[2][4], srow[2][4];
    #pragma unroll
    for (int fm = 0; fm < 2; ++fm)
        #pragma unroll
        for (int j = 0; j < 4; ++j) {
            float m = acc[fm][0][j];
            #pragma unroll
            for (int fn = 1; fn < 8; ++fn) m = fmaxf(m, acc[fm][fn][j]);
            m = fmaxf(m, __shfl_xor(m, 1));
            m = fmaxf(m, __shfl_xor(m, 2));
            m = fmaxf(m, __shfl_xor(m, 4));
            m = fmaxf(m, __shfl_xor(m, 8));
            mrow[fm][j] = m;
        }
    if ((lane & 15) == 0) {
        #pragma unroll
        for (int fm = 0; fm < 2; ++fm)
            #pragma unroll
            for (int j = 0; j < 4; ++j)
                redm[wave][fm * 16 + ((lane >> 4) << 2) + j] = mrow[fm][j];
    }
    __syncthreads();
    #pragma unroll
    for (int fm = 0; fm < 2; ++fm)
        #pragma unroll
        for (int j = 0; j < 4; ++j) {
            int rr = fm * 16 + ((lane >> 4) << 2) + j;
            mrow[fm][j] = fmaxf(fmaxf(redm[0][rr], redm[1][rr]), fmaxf(redm[2][rr], redm[3][rr]));
            srow[fm][j] = 0.f;
        }
    #pragma unroll
    for (int fm = 0; fm < 2; ++fm)
        #pragma unroll
        for (int fn = 0; fn < 8; ++fn)
            #pragma unroll
            for (int j = 0; j < 4; ++j) {
                float e = expf(acc[fm][fn][j] - mrow[fm][j]);
                acc[fm][fn][j] = e;
                srow[fm][j] += e;
            }
    #pragma unroll
    for (int fm = 0; fm < 2; ++fm)
        #pragma unroll
        for (int j = 0; j < 4; ++j) {
            float s = srow[fm][j];
            s += __shfl_xor(s, 1);
            s += __shfl_xor(s, 2);
            s += __shfl_xor(s, 4);
            s += __shfl_xor(s, 8);
            srow[fm][j] = s;
        }
    if ((lane & 15) == 0) {
        #pragma unroll
        for (int fm = 0; fm < 2; ++fm)
            #pragma unroll
            for (int j = 0; j < 4; ++j)
                reds[wave][fm * 16 + ((lane >> 4) << 2) + j] = srow[fm][j];
    }
    __syncthreads();
    #pragma unroll
    for (int fm = 0; fm < 2; ++fm)
        #pragma unroll
        for (int j = 0; j < 4; ++j) {
            int rr = fm * 16 + ((lane >> 4) << 2) + j;
            srow[fm][j] = 1.f / (reds[0][rr] + reds[1][rr] + reds[2][rr] + reds[3][rr]);
        }
    // write normalized att (bf16) back into qs (all waves done reading q after first sync)
    #pragma unroll
    for (int fm = 0; fm < 2; ++fm)
        #pragma unroll
        for (int fn = 0; fn < 8; ++fn) {
            int c = wave * 128 + fn * 16 + (lane & 15);
            int gi = c >> 3;
            #pragma unroll
            for (int j = 0; j < 4; ++j) {
                int rr = fm * 16 + ((lane >> 4) << 2) + j;
                int byteo = rr * 1024 + (((gi & 56) | ((gi & 7) ^ (rr & 7))) << 4) + ((c & 7) << 1);
                *(u16*)((char*)qs + byteo) = f2bf(acc[fm][fn][j] * srow[fm][j]);
            }
        }
    __syncthreads();
    // phase B: proj = att @ WpT^T
    v4f ac2[2][8] = {};
    for (int k0 = 0; k0 < 512; k0 += 32) {
        int gi = (k0 >> 3) + (lane >> 4);
        int ra = lane & 15, rb = 16 + (lane & 15);
        v8bf a0 = *(const v8bf*)((const char*)qs + ra * 1024 + (((gi & 56) | ((gi & 7) ^ (ra & 7))) << 4));
        v8bf a1 = *(const v8bf*)((const char*)qs + rb * 1024 + (((gi & 56) | ((gi & 7) ^ (rb & 7))) << 4));
        #pragma unroll
        for (int fn = 0; fn < 8; ++fn) {
            int e = wave * 128 + fn * 16 + (lane & 15);
            v8bf b = *(const v8bf*)&WpT[(size_t)e * 512 + k0 + ((lane >> 4) << 3)];
            ac2[0][fn] = __builtin_amdgcn_mfma_f32_16x16x32_bf16(a0, b, ac2[0][fn], 0, 0, 0);
            ac2[1][fn] = __builtin_amdgcn_mfma_f32_16x16x32_bf16(a1, b, ac2[1][fn], 0, 0, 0);
        }
    }
    #pragma unroll
    for (int fn = 0; fn < 8; ++fn) {
        int e = wave * 128 + fn * 16 + (lane & 15);
        float be = bp[e];
        #pragma unroll
        for (int fm = 0; fm < 2; ++fm)
            #pragma unroll
            for (int j = 0; j < 4; ++j) {
                int rr = fm * 16 + ((lane >> 4) << 2) + j;
                int r = blk * 32 + rr;
                float g = gelu_f(ac2[fm][fn][j] + be);
                size_t o = (size_t)r * 512 + e;
                if (accum == 0) {
                    int n = r & 1023;
                    out[o] = EPS_H * g + pe[n * 512 + e];
                } else {
                    out[o] += g;
                }
            }
    }
}

// ---------------- prep: fp32 [rows][cols] -> bf16 transposed [cols][rows]
__global__ __launch_bounds__(256)
void k_tr(const float* __restrict__ src, u16* __restrict__ dst, int rows, int cols)
{
    __shared__ float t[32][33];
    const int tid = threadIdx.x;
    const int c0 = blockIdx.x * 32, r0 = blockIdx.y * 32;
    #pragma unroll
    for (int i = 0; i < 4; ++i) {
        int idx = tid + i * 256;
        int rr = idx >> 5, cc = idx & 31;
        t[rr][cc] = src[(size_t)(r0 + rr) * cols + c0 + cc];
    }
    __syncthreads();
    #pragma unroll
    for (int i = 0; i < 4; ++i) {
        int idx = tid + i * 256;
        int rr = idx >> 5, cc = idx & 31;
        dst[(size_t)(c0 + rr) * rows + r0 + cc] = f2bf(t[cc][rr]);
    }
}

__global__ __launch_bounds__(256)
void k_pe(float* __restrict__ pe)
{
    int idx = blockIdx.x * 256 + threadIdx.x;
    pe[idx] = pe_val(idx >> 9, idx & 511);
}

extern "C" void kernel_launch(void* const* d_in, const int* in_sizes, int n_in,
                              void* d_out, int out_size, void* d_ws, size_t ws_size,
                              hipStream_t stream)
{
    const float* x    = (const float*)d_in[0];
    const float* Wqkv = (const float*)d_in[1];
    const float* bqkv = (const float*)d_in[2];
    const float* Wp   = (const float*)d_in[3];
    const float* bp   = (const float*)d_in[4];
    float* out = (float*)d_out;

    char* ws = (char*)d_ws;
    u16*   q   = (u16*)(ws);                      // 32 MiB  [32768][512]
    u16*   kT  = (u16*)(ws + 33554432);           // 32 MiB  [32][512][1024]
    u16*   vT  = (u16*)(ws + 67108864);           // 32 MiB  [32][512][1024]
    u16*   Mt  = (u16*)(ws + 100663296);          // 16 MiB  [32][512][512]
    u16*   WqT = (u16*)(ws + 117440512);          //  3 MiB  [2][1536][512]
    u16*   WpT = (u16*)(ws + 120586240);          //  1 MiB  [2][512][512]
    float* pe  = (float*)(ws + 121634816);        //  2 MiB  [1024][512]

    k_pe<<<2048, 256, 0, stream>>>(pe);
    for (int hh = 0; hh < 2; ++hh) {
        const int h = hh ? 3 : 0;   // heads 1,2 provably do not affect the output
        k_tr<<<dim3(48, 16), 256, 0, stream>>>(Wqkv + (size_t)h * 786432, WqT + (size_t)hh * 786432, 512, 1536);
        k_tr<<<dim3(16, 16), 256, 0, stream>>>(Wp   + (size_t)h * 262144, WpT + (size_t)hh * 262144, 512, 512);
    }
    for (int p = 0; p < 2; ++p) {
        const int h = p ? 3 : 0;
        k1_qkv<<<dim3(12, 256), 256, 0, stream>>>(x, WqT + (size_t)p * 786432,
                                                  bqkv + (size_t)h * 1536, q, kT, vT);
        k2_ktv<<<dim3(4, 4, 32), 256, 0, stream>>>(kT, vT, Mt);
        k3_attn<<<1024, 256, 0, stream>>>(q, Mt, WpT + (size_t)p * 262144,
                                          bp + (size_t)h * 512, pe, out, p);
    }
}

// Round 3
// 571.932 us; speedup vs baseline: 5.1641x; 1.4126x over previous
//
#include <hip/hip_runtime.h>
#include <hip/hip_bf16.h>
#include <math.h>

typedef unsigned short u16;
typedef unsigned int   u32;
typedef __bf16  v8bf  __attribute__((ext_vector_type(8)));
typedef __bf16  v4bfs __attribute__((ext_vector_type(4)));
typedef float   v4f   __attribute__((ext_vector_type(4)));

#define EPS_H 0.01f

typedef const __attribute__((address_space(1))) void* gas_t;
typedef __attribute__((address_space(3))) void* las_t;
#define GL2LDS(g,l) __builtin_amdgcn_global_load_lds((gas_t)(const void*)(g), (las_t)(void*)(l), 16, 0, 0)

__device__ __forceinline__ u16 f2bf(float f) {
    u32 x = __float_as_uint(f);
    return (u16)((x + 0x7fffu + ((x >> 16) & 1u)) >> 16);   // RNE
}
__device__ __forceinline__ float bfs(u16 v) { return __uint_as_float(((u32)v) << 16); }
__device__ __forceinline__ float selu_f(float x) {
    const float sc = 1.0507009873554805f, al = 1.6732632423543772f;
    return x > 0.f ? sc * x : sc * al * expm1f(x);
}
__device__ __forceinline__ float gelu_f(float x) {
    return 0.5f * x * (1.f + erff(x * 0.7071067811865476f));
}
__device__ __forceinline__ float pe_val(int n, int j) {
    float t = 1000.0f * ((float)(j & ~1) * (1.0f / 512.0f)) + 0.01f;
    float a = (float)n / t;
    return (j & 1) ? cosf(a) : sinf(a);
}

// fragment read from a swizzled [R][32]-bf16 LDS tile (row stride 64B)
__device__ __forceinline__ v8bf lfrag(const u16* base, int row, int lane) {
    int g = (lane >> 4) ^ ((row >> 1) & 3);
    return *(const v8bf*)((const char*)base + row * 64 + g * 16);
}

// ---------------- K1: qkv = selu(x @ W + b); q row-major, k/v stored transposed
__global__ __launch_bounds__(256)
void k1_qkv(const float* __restrict__ x, const u16* __restrict__ WT,
            const float* __restrict__ bias, u16* __restrict__ q,
            u16* __restrict__ kT, u16* __restrict__ vT)
{
    __shared__ u16 Als[128 * 32];
    __shared__ u16 Bls[128 * 32];
    const int tid = threadIdx.x, lane = tid & 63, wave = tid >> 6;
    const int col0 = blockIdx.x * 128, row0 = blockIdx.y * 128;
    const int wm = wave >> 1, wn = wave & 1;
    v4f acc[4][4] = {};
    for (int k0 = 0; k0 < 512; k0 += 32) {
        #pragma unroll
        for (int i = 0; i < 2; ++i) {                 // B via global_load_lds (pre-swizzled src)
            int ib = wave * 2 + i;
            int rl = ib * 16 + (lane >> 2);
            int gs = (lane & 3) ^ ((rl >> 1) & 3);
            GL2LDS((const char*)(WT + (size_t)(col0 + rl) * 512 + k0) + gs * 16,
                   (char*)Bls + ib * 1024);
        }
        #pragma unroll
        for (int i = 0; i < 4; ++i) {                 // A reg-staged fp32->bf16 (native cvt)
            int idx = tid + i * 256;
            int r = idx >> 3, c4 = idx & 7;
            float4 xv = *(const float4*)&x[(size_t)(row0 + r) * 512 + k0 + c4 * 4];
            v4bfs bv;
            bv[0] = (__bf16)xv.x; bv[1] = (__bf16)xv.y;
            bv[2] = (__bf16)xv.z; bv[3] = (__bf16)xv.w;
            int byteo = r * 64 + ((((c4 >> 1) ^ ((r >> 1) & 3))) << 4) + ((c4 & 1) << 3);
            *(v4bfs*)((char*)Als + byteo) = bv;
        }
        __syncthreads();
        v8bf av[4], bv2[4];
        #pragma unroll
        for (int f = 0; f < 4; ++f) {
            av[f]  = lfrag(Als, wm * 64 + f * 16 + (lane & 15), lane);
            bv2[f] = lfrag(Bls, wn * 64 + f * 16 + (lane & 15), lane);
        }
        #pragma unroll
        for (int i2 = 0; i2 < 4; ++i2)
            #pragma unroll
            for (int j2 = 0; j2 < 4; ++j2)
                acc[i2][j2] = __builtin_amdgcn_mfma_f32_16x16x32_bf16(av[i2], bv2[j2], acc[i2][j2], 0, 0, 0);
        __syncthreads();
    }
    const int region = col0 >> 9;   // 0:q 1:k 2:v (block-uniform)
    #pragma unroll
    for (int fn = 0; fn < 4; ++fn) {
        const int c = col0 + wn * 64 + fn * 16 + (lane & 15);
        const float bc = bias[c];
        #pragma unroll
        for (int fm = 0; fm < 4; ++fm) {
            const int rb = row0 + wm * 64 + fm * 16 + ((lane >> 4) << 2);
            float v0 = selu_f(acc[fm][fn][0] + bc);
            float v1 = selu_f(acc[fm][fn][1] + bc);
            float v2 = selu_f(acc[fm][fn][2] + bc);
            float v3 = selu_f(acc[fm][fn][3] + bc);
            if (region == 0) {
                q[(size_t)(rb + 0) * 512 + c] = f2bf(v0);
                q[(size_t)(rb + 1) * 512 + c] = f2bf(v1);
                q[(size_t)(rb + 2) * 512 + c] = f2bf(v2);
                q[(size_t)(rb + 3) * 512 + c] = f2bf(v3);
            } else {
                ushort4 st; st.x = f2bf(v0); st.y = f2bf(v1); st.z = f2bf(v2); st.w = f2bf(v3);
                const int seq = rb >> 10, n = rb & 1023;
                u16* dst = (region == 1) ? kT : vT;
                const int cc = c - ((region == 1) ? 512 : 1024);
                *(ushort4*)&dst[(size_t)seq * 524288 + (size_t)cc * 1024 + n] = st;
            }
        }
    }
}

// ---------------- K2: Mt[p][d] = (1/512) * sum_m K[m][d] V[m][p]   (per seq)
__global__ __launch_bounds__(256)
void k2_ktv(const u16* __restrict__ kT, const u16* __restrict__ vT, u16* __restrict__ Mt)
{
    __shared__ u16 Als[128 * 32];
    __shared__ u16 Bls[128 * 32];
    const int tid = threadIdx.x, lane = tid & 63, wave = tid >> 6;
    const int d0 = blockIdx.x * 128, p0 = blockIdx.y * 128, seq = blockIdx.z;
    const u16* Ab = kT + (size_t)seq * 524288;
    const u16* Bb = vT + (size_t)seq * 524288;
    const int wm = wave >> 1, wn = wave & 1;
    v4f acc[4][4] = {};
    for (int m0 = 0; m0 < 1024; m0 += 32) {
        #pragma unroll
        for (int i = 0; i < 2; ++i) {
            int ib = wave * 2 + i;
            int rl = ib * 16 + (lane >> 2);
            int gs = (lane & 3) ^ ((rl >> 1) & 3);
            GL2LDS((const char*)(Ab + (size_t)(d0 + rl) * 1024 + m0) + gs * 16, (char*)Als + ib * 1024);
            GL2LDS((const char*)(Bb + (size_t)(p0 + rl) * 1024 + m0) + gs * 16, (char*)Bls + ib * 1024);
        }
        __syncthreads();
        v8bf av[4], bv[4];
        #pragma unroll
        for (int f = 0; f < 4; ++f) {
            av[f] = lfrag(Als, wm * 64 + f * 16 + (lane & 15), lane);
            bv[f] = lfrag(Bls, wn * 64 + f * 16 + (lane & 15), lane);
        }
        #pragma unroll
        for (int i2 = 0; i2 < 4; ++i2)
            #pragma unroll
            for (int j2 = 0; j2 < 4; ++j2)
                acc[i2][j2] = __builtin_amdgcn_mfma_f32_16x16x32_bf16(av[i2], bv[j2], acc[i2][j2], 0, 0, 0);
        __syncthreads();
    }
    #pragma unroll
    for (int fn = 0; fn < 4; ++fn) {
        const int p = p0 + wn * 64 + fn * 16 + (lane & 15);
        #pragma unroll
        for (int fm = 0; fm < 4; ++fm) {
            const int d = d0 + wm * 64 + fm * 16 + ((lane >> 4) << 2);
            ushort4 st;
            st.x = f2bf(acc[fm][fn][0] * (1.f / 512.f));
            st.y = f2bf(acc[fm][fn][1] * (1.f / 512.f));
            st.z = f2bf(acc[fm][fn][2] * (1.f / 512.f));
            st.w = f2bf(acc[fm][fn][3] * (1.f / 512.f));
            *(ushort4*)&Mt[(size_t)seq * 262144 + (size_t)p * 512 + d] = st;   // transposed store
        }
    }
}

// ---------------- K3a: S[n][p] = sum_d q[n][d] * Mt[p][d]   (per-seq Mt), S bf16
__global__ __launch_bounds__(256)
void k3a_s(const u16* __restrict__ q, const u16* __restrict__ Mt, u16* __restrict__ S)
{
    __shared__ u16 Als[128 * 32];
    __shared__ u16 Bls[128 * 32];
    const int tid = threadIdx.x, lane = tid & 63, wave = tid >> 6;
    const int p0 = blockIdx.x * 128, row0 = blockIdx.y * 128;
    const int seq = row0 >> 10;
    const u16* Ab = q + (size_t)row0 * 512;
    const u16* Bb = Mt + (size_t)seq * 262144 + (size_t)p0 * 512;
    const int wm = wave >> 1, wn = wave & 1;
    v4f acc[4][4] = {};
    for (int k0 = 0; k0 < 512; k0 += 32) {
        #pragma unroll
        for (int i = 0; i < 2; ++i) {
            int ib = wave * 2 + i;
            int rl = ib * 16 + (lane >> 2);
            int gs = (lane & 3) ^ ((rl >> 1) & 3);
            GL2LDS((const char*)(Ab + (size_t)rl * 512 + k0) + gs * 16, (char*)Als + ib * 1024);
            GL2LDS((const char*)(Bb + (size_t)rl * 512 + k0) + gs * 16, (char*)Bls + ib * 1024);
        }
        __syncthreads();
        v8bf av[4], bv[4];
        #pragma unroll
        for (int f = 0; f < 4; ++f) {
            av[f] = lfrag(Als, wm * 64 + f * 16 + (lane & 15), lane);
            bv[f] = lfrag(Bls, wn * 64 + f * 16 + (lane & 15), lane);
        }
        #pragma unroll
        for (int i2 = 0; i2 < 4; ++i2)
            #pragma unroll
            for (int j2 = 0; j2 < 4; ++j2)
                acc[i2][j2] = __builtin_amdgcn_mfma_f32_16x16x32_bf16(av[i2], bv[j2], acc[i2][j2], 0, 0, 0);
        __syncthreads();
    }
    #pragma unroll
    for (int fn = 0; fn < 4; ++fn) {
        const int c = p0 + wn * 64 + fn * 16 + (lane & 15);
        #pragma unroll
        for (int fm = 0; fm < 4; ++fm) {
            const int rb = row0 + wm * 64 + fm * 16 + ((lane >> 4) << 2);
            S[(size_t)(rb + 0) * 512 + c] = f2bf(acc[fm][fn][0]);
            S[(size_t)(rb + 1) * 512 + c] = f2bf(acc[fm][fn][1]);
            S[(size_t)(rb + 2) * 512 + c] = f2bf(acc[fm][fn][2]);
            S[(size_t)(rb + 3) * 512 + c] = f2bf(acc[fm][fn][3]);
        }
    }
}

// ---------------- K3b: in-place row softmax over 512 cols (one wave per row)
__global__ __launch_bounds__(256)
void k3b_sm(u16* __restrict__ S)
{
    const int row  = blockIdx.x * 4 + (threadIdx.x >> 6);
    const int lane = threadIdx.x & 63;
    u16* rp = S + (size_t)row * 512 + lane * 8;
    ushort4 u0 = *(const ushort4*)rp;
    ushort4 u1 = *(const ushort4*)(rp + 4);
    float f[8] = {bfs(u0.x), bfs(u0.y), bfs(u0.z), bfs(u0.w),
                  bfs(u1.x), bfs(u1.y), bfs(u1.z), bfs(u1.w)};
    float m = f[0];
    #pragma unroll
    for (int j = 1; j < 8; ++j) m = fmaxf(m, f[j]);
    #pragma unroll
    for (int off = 32; off > 0; off >>= 1) m = fmaxf(m, __shfl_xor(m, off));
    float s = 0.f;
    #pragma unroll
    for (int j = 0; j < 8; ++j) { f[j] = expf(f[j] - m); s += f[j]; }
    #pragma unroll
    for (int off = 32; off > 0; off >>= 1) s += __shfl_xor(s, off);
    const float inv = 1.0f / s;
    ushort4 o0, o1;
    o0.x = f2bf(f[0] * inv); o0.y = f2bf(f[1] * inv);
    o0.z = f2bf(f[2] * inv); o0.w = f2bf(f[3] * inv);
    o1.x = f2bf(f[4] * inv); o1.y = f2bf(f[5] * inv);
    o1.z = f2bf(f[6] * inv); o1.w = f2bf(f[7] * inv);
    *(ushort4*)rp = o0;
    *(ushort4*)(rp + 4) = o1;
}

// ---------------- K3c: out (+)= gelu(att @ WpT^T + bp) [+ EPS scale + pe on first head]
__global__ __launch_bounds__(256)
void k3c_proj(const u16* __restrict__ att, const u16* __restrict__ WpT,
              const float* __restrict__ bp, const float* __restrict__ pe,
              float* __restrict__ out, const int accum)
{
    __shared__ u16 Als[128 * 32];
    __shared__ u16 Bls[128 * 32];
    const int tid = threadIdx.x, lane = tid & 63, wave = tid >> 6;
    const int e0 = blockIdx.x * 128, row0 = blockIdx.y * 128;
    const u16* Ab = att + (size_t)row0 * 512;
    const u16* Bb = WpT + (size_t)e0 * 512;
    const int wm = wave >> 1, wn = wave & 1;
    v4f acc[4][4] = {};
    for (int k0 = 0; k0 < 512; k0 += 32) {
        #pragma unroll
        for (int i = 0; i < 2; ++i) {
            int ib = wave * 2 + i;
            int rl = ib * 16 + (lane >> 2);
            int gs = (lane & 3) ^ ((rl >> 1) & 3);
            GL2LDS((const char*)(Ab + (size_t)rl * 512 + k0) + gs * 16, (char*)Als + ib * 1024);
            GL2LDS((const char*)(Bb + (size_t)rl * 512 + k0) + gs * 16, (char*)Bls + ib * 1024);
        }
        __syncthreads();
        v8bf av[4], bv[4];
        #pragma unroll
        for (int f = 0; f < 4; ++f) {
            av[f] = lfrag(Als, wm * 64 + f * 16 + (lane & 15), lane);
            bv[f] = lfrag(Bls, wn * 64 + f * 16 + (lane & 15), lane);
        }
        #pragma unroll
        for (int i2 = 0; i2 < 4; ++i2)
            #pragma unroll
            for (int j2 = 0; j2 < 4; ++j2)
                acc[i2][j2] = __builtin_amdgcn_mfma_f32_16x16x32_bf16(av[i2], bv[j2], acc[i2][j2], 0, 0, 0);
        __syncthreads();
    }
    #pragma unroll
    for (int fn = 0; fn < 4; ++fn) {
        const int e = e0 + wn * 64 + fn * 16 + (lane & 15);
        const float be = bp[e];
        #pragma unroll
        for (int fm = 0; fm < 4; ++fm) {
            const int rb = row0 + wm * 64 + fm * 16 + ((lane >> 4) << 2);
            #pragma unroll
            for (int j = 0; j < 4; ++j) {
                const int r = rb + j;
                const float g = gelu_f(acc[fm][fn][j] + be);
                const size_t o = (size_t)r * 512 + e;
                if (accum == 0) out[o] = EPS_H * g + pe[(r & 1023) * 512 + e];
                else            out[o] += g;
            }
        }
    }
}

// ---------------- prep: fp32 [rows][cols] -> bf16 transposed [cols][rows]
__global__ __launch_bounds__(256)
void k_tr(const float* __restrict__ src, u16* __restrict__ dst, int rows, int cols)
{
    __shared__ float t[32][33];
    const int tid = threadIdx.x;
    const int c0 = blockIdx.x * 32, r0 = blockIdx.y * 32;
    #pragma unroll
    for (int i = 0; i < 4; ++i) {
        int idx = tid + i * 256;
        int rr = idx >> 5, cc = idx & 31;
        t[rr][cc] = src[(size_t)(r0 + rr) * cols + c0 + cc];
    }
    __syncthreads();
    #pragma unroll
    for (int i = 0; i < 4; ++i) {
        int idx = tid + i * 256;
        int rr = idx >> 5, cc = idx & 31;
        dst[(size_t)(c0 + rr) * rows + r0 + cc] = f2bf(t[cc][rr]);
    }
}

__global__ __launch_bounds__(256)
void k_pe(float* __restrict__ pe)
{
    int idx = blockIdx.x * 256 + threadIdx.x;
    pe[idx] = pe_val(idx >> 9, idx & 511);
}

extern "C" void kernel_launch(void* const* d_in, const int* in_sizes, int n_in,
                              void* d_out, int out_size, void* d_ws, size_t ws_size,
                              hipStream_t stream)
{
    const float* x    = (const float*)d_in[0];
    const float* Wqkv = (const float*)d_in[1];
    const float* bqkv = (const float*)d_in[2];
    const float* Wp   = (const float*)d_in[3];
    const float* bp   = (const float*)d_in[4];
    float* out = (float*)d_out;

    char* ws = (char*)d_ws;
    u16*   q   = (u16*)(ws);                      // 32 MiB  [32768][512]
    u16*   kT  = (u16*)(ws + 33554432);           // 32 MiB  [32][512][1024]; reused as S/att
    u16*   vT  = (u16*)(ws + 67108864);           // 32 MiB  [32][512][1024]
    u16*   Mt  = (u16*)(ws + 100663296);          // 16 MiB  [32][512][512]
    u16*   WqT = (u16*)(ws + 117440512);          //  3 MiB  [2][1536][512]
    u16*   WpT = (u16*)(ws + 120586240);          //  1 MiB  [2][512][512]
    float* pe  = (float*)(ws + 121634816);        //  2 MiB  [1024][512]
    u16*   S   = kT;                              // S/att alias (kT dead after K2)

    k_pe<<<2048, 256, 0, stream>>>(pe);
    for (int hh = 0; hh < 2; ++hh) {
        const int h = hh ? 3 : 0;   // heads 1,2 provably do not affect the output
        k_tr<<<dim3(48, 16), 256, 0, stream>>>(Wqkv + (size_t)h * 786432, WqT + (size_t)hh * 786432, 512, 1536);
        k_tr<<<dim3(16, 16), 256, 0, stream>>>(Wp   + (size_t)h * 262144, WpT + (size_t)hh * 262144, 512, 512);
    }
    for (int p = 0; p < 2; ++p) {
        const int h = p ? 3 : 0;
        k1_qkv<<<dim3(12, 256), 256, 0, stream>>>(x, WqT + (size_t)p * 786432,
                                                  bqkv + (size_t)h * 1536, q, kT, vT);
        k2_ktv<<<dim3(4, 4, 32), 256, 0, stream>>>(kT, vT, Mt);
        k3a_s<<<dim3(4, 256), 256, 0, stream>>>(q, Mt, S);
        k3b_sm<<<8192, 256, 0, stream>>>(S);
        k3c_proj<<<dim3(4, 256), 256, 0, stream>>>(S, WpT + (size_t)p * 262144,
                                                   bp + (size_t)h * 512, pe, out, p);
    }
}

// Round 4
// 544.871 us; speedup vs baseline: 5.4206x; 1.0497x over previous
//
#include <hip/hip_runtime.h>
#include <hip/hip_bf16.h>
#include <math.h>

typedef unsigned short u16;
typedef unsigned int   u32;
typedef __bf16  v8bf  __attribute__((ext_vector_type(8)));
typedef float   v4f   __attribute__((ext_vector_type(4)));

#define EPS_H 0.01f

typedef const __attribute__((address_space(1))) void* gas_t;
typedef __attribute__((address_space(3))) void* las_t;
#define GL2LDS(g,l) __builtin_amdgcn_global_load_lds((gas_t)(const void*)(g), (las_t)(void*)(l), 16, 0, 0)

__device__ __forceinline__ u16 f2bf(float f) {
    u32 x = __float_as_uint(f);
    return (u16)((x + 0x7fffu + ((x >> 16) & 1u)) >> 16);   // RNE
}
__device__ __forceinline__ float bfs(u16 v) { return __uint_as_float(((u32)v) << 16); }
__device__ __forceinline__ float selu_f(float x) {
    const float sc = 1.0507009873554805f, al = 1.6732632423543772f;
    return x > 0.f ? sc * x : sc * al * expm1f(x);
}
__device__ __forceinline__ float gelu_f(float x) {
    return 0.5f * x * (1.f + erff(x * 0.7071067811865476f));
}
__device__ __forceinline__ float pe_val(int n, int j) {
    float t = 1000.0f * ((float)(j & ~1) * (1.0f / 512.0f)) + 0.01f;
    float a = (float)n / t;
    return (j & 1) ? cosf(a) : sinf(a);
}

// fragment read from a swizzled [R][32]-bf16 LDS tile (row stride 64B)
__device__ __forceinline__ v8bf lfrag(const u16* base, int row, int lane) {
    int g = (lane >> 4) ^ ((row >> 1) & 3);
    return *(const v8bf*)((const char*)base + row * 64 + g * 16);
}

// ---------------- K0: x fp32 -> bf16 (once)
__global__ __launch_bounds__(256)
void k_xbf(const float* __restrict__ x, u16* __restrict__ xbf)
{
    const size_t i = ((size_t)blockIdx.x * 256 + threadIdx.x) * 8;
    float4 a = *(const float4*)&x[i];
    float4 b = *(const float4*)&x[i + 4];
    ushort4 o0, o1;
    o0.x = f2bf(a.x); o0.y = f2bf(a.y); o0.z = f2bf(a.z); o0.w = f2bf(a.w);
    o1.x = f2bf(b.x); o1.y = f2bf(b.y); o1.z = f2bf(b.z); o1.w = f2bf(b.w);
    *(ushort4*)&xbf[i] = o0;
    *(ushort4*)&xbf[i + 4] = o1;
}

// ---------------- K1: qkv = selu(x @ W + b); q row-major, k/v stored transposed (16-seq chunk)
__global__ __launch_bounds__(256)
void k1_qkv(const u16* __restrict__ xbf, const u16* __restrict__ WT,
            const float* __restrict__ bias, u16* __restrict__ q,
            u16* __restrict__ kT, u16* __restrict__ vT)
{
    __shared__ u16 Als[128 * 32];
    __shared__ u16 Bls[128 * 32];
    const int tid = threadIdx.x, lane = tid & 63, wave = tid >> 6;
    // XCD-aware bijective swizzle (nwg = 12*128 = 1536, 1536/8 = 192)
    const int orig = blockIdx.x + blockIdx.y * 12;
    const int swz  = (orig & 7) * 192 + (orig >> 3);
    const int col0 = (swz % 12) * 128, row0 = (swz / 12) * 128;
    const int wm = wave >> 1, wn = wave & 1;
    v4f acc[4][4] = {};
    for (int k0 = 0; k0 < 512; k0 += 32) {
        #pragma unroll
        for (int i = 0; i < 2; ++i) {                 // A and B via global_load_lds (pre-swizzled src)
            int ib = wave * 2 + i;
            int rl = ib * 16 + (lane >> 2);
            int gs = (lane & 3) ^ ((rl >> 1) & 3);
            GL2LDS((const char*)(xbf + (size_t)(row0 + rl) * 512 + k0) + gs * 16,
                   (char*)Als + ib * 1024);
            GL2LDS((const char*)(WT + (size_t)(col0 + rl) * 512 + k0) + gs * 16,
                   (char*)Bls + ib * 1024);
        }
        __syncthreads();
        v8bf av[4], bv2[4];
        #pragma unroll
        for (int f = 0; f < 4; ++f) {
            av[f]  = lfrag(Als, wm * 64 + f * 16 + (lane & 15), lane);
            bv2[f] = lfrag(Bls, wn * 64 + f * 16 + (lane & 15), lane);
        }
        #pragma unroll
        for (int i2 = 0; i2 < 4; ++i2)
            #pragma unroll
            for (int j2 = 0; j2 < 4; ++j2)
                acc[i2][j2] = __builtin_amdgcn_mfma_f32_16x16x32_bf16(av[i2], bv2[j2], acc[i2][j2], 0, 0, 0);
        __syncthreads();
    }
    const int region = col0 >> 9;   // 0:q 1:k 2:v (block-uniform)
    #pragma unroll
    for (int fn = 0; fn < 4; ++fn) {
        const int c = col0 + wn * 64 + fn * 16 + (lane & 15);
        const float bc = bias[c];
        #pragma unroll
        for (int fm = 0; fm < 4; ++fm) {
            const int rb = row0 + wm * 64 + fm * 16 + ((lane >> 4) << 2);
            float v0 = selu_f(acc[fm][fn][0] + bc);
            float v1 = selu_f(acc[fm][fn][1] + bc);
            float v2 = selu_f(acc[fm][fn][2] + bc);
            float v3 = selu_f(acc[fm][fn][3] + bc);
            if (region == 0) {
                q[(size_t)(rb + 0) * 512 + c] = f2bf(v0);
                q[(size_t)(rb + 1) * 512 + c] = f2bf(v1);
                q[(size_t)(rb + 2) * 512 + c] = f2bf(v2);
                q[(size_t)(rb + 3) * 512 + c] = f2bf(v3);
            } else {
                ushort4 st; st.x = f2bf(v0); st.y = f2bf(v1); st.z = f2bf(v2); st.w = f2bf(v3);
                const int seq = rb >> 10, n = rb & 1023;
                u16* dst = (region == 1) ? kT : vT;
                const int cc = c - ((region == 1) ? 512 : 1024);
                *(ushort4*)&dst[(size_t)seq * 524288 + (size_t)cc * 1024 + n] = st;
            }
        }
    }
}

// ---------------- K2: Mt[p][d] = (1/512) * sum_m K[m][d] V[m][p]   (per seq, 16-seq chunk)
__global__ __launch_bounds__(256)
void k2_ktv(const u16* __restrict__ kT, const u16* __restrict__ vT, u16* __restrict__ Mt)
{
    __shared__ u16 Als[128 * 32];
    __shared__ u16 Bls[128 * 32];
    const int tid = threadIdx.x, lane = tid & 63, wave = tid >> 6;
    const int d0 = blockIdx.x * 128, p0 = blockIdx.y * 128, seq = blockIdx.z;
    const u16* Ab = kT + (size_t)seq * 524288;
    const u16* Bb = vT + (size_t)seq * 524288;
    const int wm = wave >> 1, wn = wave & 1;
    v4f acc[4][4] = {};
    for (int m0 = 0; m0 < 1024; m0 += 32) {
        #pragma unroll
        for (int i = 0; i < 2; ++i) {
            int ib = wave * 2 + i;
            int rl = ib * 16 + (lane >> 2);
            int gs = (lane & 3) ^ ((rl >> 1) & 3);
            GL2LDS((const char*)(Ab + (size_t)(d0 + rl) * 1024 + m0) + gs * 16, (char*)Als + ib * 1024);
            GL2LDS((const char*)(Bb + (size_t)(p0 + rl) * 1024 + m0) + gs * 16, (char*)Bls + ib * 1024);
        }
        __syncthreads();
        v8bf av[4], bv[4];
        #pragma unroll
        for (int f = 0; f < 4; ++f) {
            av[f] = lfrag(Als, wm * 64 + f * 16 + (lane & 15), lane);
            bv[f] = lfrag(Bls, wn * 64 + f * 16 + (lane & 15), lane);
        }
        #pragma unroll
        for (int i2 = 0; i2 < 4; ++i2)
            #pragma unroll
            for (int j2 = 0; j2 < 4; ++j2)
                acc[i2][j2] = __builtin_amdgcn_mfma_f32_16x16x32_bf16(av[i2], bv[j2], acc[i2][j2], 0, 0, 0);
        __syncthreads();
    }
    #pragma unroll
    for (int fn = 0; fn < 4; ++fn) {
        const int p = p0 + wn * 64 + fn * 16 + (lane & 15);
        #pragma unroll
        for (int fm = 0; fm < 4; ++fm) {
            const int d = d0 + wm * 64 + fm * 16 + ((lane >> 4) << 2);
            ushort4 st;
            st.x = f2bf(acc[fm][fn][0] * (1.f / 512.f));
            st.y = f2bf(acc[fm][fn][1] * (1.f / 512.f));
            st.z = f2bf(acc[fm][fn][2] * (1.f / 512.f));
            st.w = f2bf(acc[fm][fn][3] * (1.f / 512.f));
            *(ushort4*)&Mt[(size_t)seq * 262144 + (size_t)p * 512 + d] = st;   // transposed store
        }
    }
}

// ---------------- K3a: S[n][p] = sum_d q[n][d] * Mt[p][d]   (per-seq Mt), S bf16
__global__ __launch_bounds__(256)
void k3a_s(const u16* __restrict__ q, const u16* __restrict__ Mt, u16* __restrict__ S)
{
    __shared__ u16 Als[128 * 32];
    __shared__ u16 Bls[128 * 32];
    const int tid = threadIdx.x, lane = tid & 63, wave = tid >> 6;
    const int p0 = blockIdx.x * 128, row0 = blockIdx.y * 128;
    const int seq = row0 >> 10;
    const u16* Ab = q + (size_t)row0 * 512;
    const u16* Bb = Mt + (size_t)seq * 262144 + (size_t)p0 * 512;
    const int wm = wave >> 1, wn = wave & 1;
    v4f acc[4][4] = {};
    for (int k0 = 0; k0 < 512; k0 += 32) {
        #pragma unroll
        for (int i = 0; i < 2; ++i) {
            int ib = wave * 2 + i;
            int rl = ib * 16 + (lane >> 2);
            int gs = (lane & 3) ^ ((rl >> 1) & 3);
            GL2LDS((const char*)(Ab + (size_t)rl * 512 + k0) + gs * 16, (char*)Als + ib * 1024);
            GL2LDS((const char*)(Bb + (size_t)rl * 512 + k0) + gs * 16, (char*)Bls + ib * 1024);
        }
        __syncthreads();
        v8bf av[4], bv[4];
        #pragma unroll
        for (int f = 0; f < 4; ++f) {
            av[f] = lfrag(Als, wm * 64 + f * 16 + (lane & 15), lane);
            bv[f] = lfrag(Bls, wn * 64 + f * 16 + (lane & 15), lane);
        }
        #pragma unroll
        for (int i2 = 0; i2 < 4; ++i2)
            #pragma unroll
            for (int j2 = 0; j2 < 4; ++j2)
                acc[i2][j2] = __builtin_amdgcn_mfma_f32_16x16x32_bf16(av[i2], bv[j2], acc[i2][j2], 0, 0, 0);
        __syncthreads();
    }
    #pragma unroll
    for (int fn = 0; fn < 4; ++fn) {
        const int c = p0 + wn * 64 + fn * 16 + (lane & 15);
        #pragma unroll
        for (int fm = 0; fm < 4; ++fm) {
            const int rb = row0 + wm * 64 + fm * 16 + ((lane >> 4) << 2);
            S[(size_t)(rb + 0) * 512 + c] = f2bf(acc[fm][fn][0]);
            S[(size_t)(rb + 1) * 512 + c] = f2bf(acc[fm][fn][1]);
            S[(size_t)(rb + 2) * 512 + c] = f2bf(acc[fm][fn][2]);
            S[(size_t)(rb + 3) * 512 + c] = f2bf(acc[fm][fn][3]);
        }
    }
}

// ---------------- K3b: in-place row softmax over 512 cols (one wave per row)
__global__ __launch_bounds__(256)
void k3b_sm(u16* __restrict__ S)
{
    const int row  = blockIdx.x * 4 + (threadIdx.x >> 6);
    const int lane = threadIdx.x & 63;
    u16* rp = S + (size_t)row * 512 + lane * 8;
    ushort4 u0 = *(const ushort4*)rp;
    ushort4 u1 = *(const ushort4*)(rp + 4);
    float f[8] = {bfs(u0.x), bfs(u0.y), bfs(u0.z), bfs(u0.w),
                  bfs(u1.x), bfs(u1.y), bfs(u1.z), bfs(u1.w)};
    float m = f[0];
    #pragma unroll
    for (int j = 1; j < 8; ++j) m = fmaxf(m, f[j]);
    #pragma unroll
    for (int off = 32; off > 0; off >>= 1) m = fmaxf(m, __shfl_xor(m, off));
    float s = 0.f;
    #pragma unroll
    for (int j = 0; j < 8; ++j) { f[j] = expf(f[j] - m); s += f[j]; }
    #pragma unroll
    for (int off = 32; off > 0; off >>= 1) s += __shfl_xor(s, off);
    const float inv = 1.0f / s;
    ushort4 o0, o1;
    o0.x = f2bf(f[0] * inv); o0.y = f2bf(f[1] * inv);
    o0.z = f2bf(f[2] * inv); o0.w = f2bf(f[3] * inv);
    o1.x = f2bf(f[4] * inv); o1.y = f2bf(f[5] * inv);
    o1.z = f2bf(f[6] * inv); o1.w = f2bf(f[7] * inv);
    *(ushort4*)rp = o0;
    *(ushort4*)(rp + 4) = o1;
}

// ---------------- K3c: mode 0: out = gelu(att@WpT^T + bp)           (head 0, fp32 store)
//                       mode 1: out = gelu(...) + EPS*out + pe       (head 3, final)
__global__ __launch_bounds__(256)
void k3c_proj(const u16* __restrict__ att, const u16* __restrict__ WpT,
              const float* __restrict__ bp, const float* __restrict__ pe,
              float* __restrict__ out, const int mode, const int rowbase)
{
    __shared__ u16 Als[128 * 32];
    __shared__ u16 Bls[128 * 32];
    const int tid = threadIdx.x, lane = tid & 63, wave = tid >> 6;
    const int e0 = blockIdx.x * 128, row0 = blockIdx.y * 128;
    const u16* Ab = att + (size_t)row0 * 512;
    const u16* Bb = WpT + (size_t)e0 * 512;
    const int wm = wave >> 1, wn = wave & 1;
    v4f acc[4][4] = {};
    for (int k0 = 0; k0 < 512; k0 += 32) {
        #pragma unroll
        for (int i = 0; i < 2; ++i) {
            int ib = wave * 2 + i;
            int rl = ib * 16 + (lane >> 2);
            int gs = (lane & 3) ^ ((rl >> 1) & 3);
            GL2LDS((const char*)(Ab + (size_t)rl * 512 + k0) + gs * 16, (char*)Als + ib * 1024);
            GL2LDS((const char*)(Bb + (size_t)rl * 512 + k0) + gs * 16, (char*)Bls + ib * 1024);
        }
        __syncthreads();
        v8bf av[4], bv[4];
        #pragma unroll
        for (int f = 0; f < 4; ++f) {
            av[f] = lfrag(Als, wm * 64 + f * 16 + (lane & 15), lane);
            bv[f] = lfrag(Bls, wn * 64 + f * 16 + (lane & 15), lane);
        }
        #pragma unroll
        for (int i2 = 0; i2 < 4; ++i2)
            #pragma unroll
            for (int j2 = 0; j2 < 4; ++j2)
                acc[i2][j2] = __builtin_amdgcn_mfma_f32_16x16x32_bf16(av[i2], bv[j2], acc[i2][j2], 0, 0, 0);
        __syncthreads();
    }
    #pragma unroll
    for (int fn = 0; fn < 4; ++fn) {
        const int e = e0 + wn * 64 + fn * 16 + (lane & 15);
        const float be = bp[e];
        #pragma unroll
        for (int fm = 0; fm < 4; ++fm) {
            const int rb = row0 + wm * 64 + fm * 16 + ((lane >> 4) << 2);
            #pragma unroll
            for (int j = 0; j < 4; ++j) {
                const int r = rowbase + rb + j;
                const float g = gelu_f(acc[fm][fn][j] + be);
                const size_t o = (size_t)r * 512 + e;
                if (mode == 0) out[o] = g;
                else           out[o] = g + EPS_H * out[o] + pe[(r & 1023) * 512 + e];
            }
        }
    }
}

// ---------------- prep: fp32 [rows][cols] -> bf16 transposed [cols][rows]
__global__ __launch_bounds__(256)
void k_tr(const float* __restrict__ src, u16* __restrict__ dst, int rows, int cols)
{
    __shared__ float t[32][33];
    const int tid = threadIdx.x;
    const int c0 = blockIdx.x * 32, r0 = blockIdx.y * 32;
    #pragma unroll
    for (int i = 0; i < 4; ++i) {
        int idx = tid + i * 256;
        int rr = idx >> 5, cc = idx & 31;
        t[rr][cc] = src[(size_t)(r0 + rr) * cols + c0 + cc];
    }
    __syncthreads();
    #pragma unroll
    for (int i = 0; i < 4; ++i) {
        int idx = tid + i * 256;
        int rr = idx >> 5, cc = idx & 31;
        dst[(size_t)(c0 + rr) * rows + r0 + cc] = f2bf(t[cc][rr]);
    }
}

__global__ __launch_bounds__(256)
void k_pe(float* __restrict__ pe)
{
    int idx = blockIdx.x * 256 + threadIdx.x;
    pe[idx] = pe_val(idx >> 9, idx & 511);
}

extern "C" void kernel_launch(void* const* d_in, const int* in_sizes, int n_in,
                              void* d_out, int out_size, void* d_ws, size_t ws_size,
                              hipStream_t stream)
{
    const float* x    = (const float*)d_in[0];
    const float* Wqkv = (const float*)d_in[1];
    const float* bqkv = (const float*)d_in[2];
    const float* Wp   = (const float*)d_in[3];
    const float* bp   = (const float*)d_in[4];
    float* out = (float*)d_out;

    char* ws = (char*)d_ws;
    u16*   xbf = (u16*)(ws);                      // 32 MiB  [32768][512] bf16
    u16*   q   = (u16*)(ws + 33554432);           // 16 MiB  [16384][512]      (chunk)
    u16*   kT  = (u16*)(ws + 50331648);           // 16 MiB  [16][512][1024]   (chunk; reused as S)
    u16*   vT  = (u16*)(ws + 67108864);           // 16 MiB  [16][512][1024]   (chunk)
    u16*   Mt  = (u16*)(ws + 83886080);           //  8 MiB  [16][512][512]    (chunk)
    u16*   WqT = (u16*)(ws + 92274688);           //  3 MiB  [2][1536][512]
    u16*   WpT = (u16*)(ws + 95420416);           //  1 MiB  [2][512][512]
    float* pe  = (float*)(ws + 96468992);         //  2 MiB  [1024][512]
    u16*   S   = kT;                              // S/att alias (kT dead after K2)

    k_xbf<<<8192, 256, 0, stream>>>(x, xbf);
    k_pe<<<2048, 256, 0, stream>>>(pe);
    for (int hh = 0; hh < 2; ++hh) {
        const int h = hh ? 3 : 0;   // heads 1,2 provably do not affect the output
        k_tr<<<dim3(48, 16), 256, 0, stream>>>(Wqkv + (size_t)h * 786432, WqT + (size_t)hh * 786432, 512, 1536);
        k_tr<<<dim3(16, 16), 256, 0, stream>>>(Wp   + (size_t)h * 262144, WpT + (size_t)hh * 262144, 512, 512);
    }
    for (int p = 0; p < 2; ++p) {
        const int h = p ? 3 : 0;
        for (int ck = 0; ck < 2; ++ck) {
            const u16* xc = xbf + (size_t)ck * 16384 * 512;
            k1_qkv<<<dim3(12, 128), 256, 0, stream>>>(xc, WqT + (size_t)p * 786432,
                                                      bqkv + (size_t)h * 1536, q, kT, vT);
            k2_ktv<<<dim3(4, 4, 16), 256, 0, stream>>>(kT, vT, Mt);
            k3a_s<<<dim3(4, 128), 256, 0, stream>>>(q, Mt, S);
            k3b_sm<<<4096, 256, 0, stream>>>(S);
            k3c_proj<<<dim3(4, 128), 256, 0, stream>>>(S, WpT + (size_t)p * 262144,
                                                       bp + (size_t)h * 512, pe, out, p, ck * 16384);
        }
    }
}